// Round 3
// baseline (134.556 us; speedup 1.0000x reference)
//
#include <hip/hip_runtime.h>
#include <math.h>

#define B_    16
#define D_    512
#define T_    4096
#define CBN_  1024
#define CD_   8
#define NTOK_ (B_ * T_)   // 65536

// ws layout (float offsets)
#define WS_WIN_T   0                        // [512][8]  w_in transposed: [i][o]
#define WS_WOUT    4096                     // [512][8]  w_out: [o][j]
#define WS_CBN     8192                     // [1024][9] cb_n[8], c=sum(cb_n^2)
#define WS_QN      17408                    // [1024][2] ||q||, ||q||^2
#define WS_ZEP     19456                    // [8][65536][8] z_e partials (chunk-major)
#define WS_IDX     (19456 + 4194304)        // int[65536]
#define WS_BPART   (19456 + 4194304 + 65536) // float[1024] loss partials

#define OUT_OFF_LOSS 33554432               // commitment[16], then codebook[16]
#define OUT_OFF_IDX  33554464               // indices as float [65536]

// ---------------- k0: prepare weight-normed weights + normalized codebook ----
__global__ __launch_bounds__(256) void k0_prep(const float* __restrict__ v_in,
                                               const float* __restrict__ g_in,
                                               const float* __restrict__ v_out,
                                               const float* __restrict__ g_out,
                                               const float* __restrict__ codebook,
                                               float* __restrict__ ws) {
    int bid = blockIdx.x, tid = threadIdx.x;
    if (bid < 4) {
        // normalized codebook + c, plus ||q||, ||q||^2 table
        int e = bid * 256 + tid;
        const float* c = codebook + (size_t)e * 8;
        float v[8]; float s = 0.f;
#pragma unroll
        for (int j = 0; j < 8; ++j) { v[j] = c[j]; s += v[j] * v[j]; }
        float qn = sqrtf(s);
        float rn = 1.0f / fmaxf(qn, 1e-12f);
        float cs = 0.f;
        float* o = ws + WS_CBN + (size_t)e * 9;
#pragma unroll
        for (int j = 0; j < 8; ++j) { float cn = v[j] * rn; o[j] = cn; cs += cn * cn; }
        o[8] = cs;
        ws[WS_QN + e * 2]     = qn;
        ws[WS_QN + e * 2 + 1] = s;
    } else if (bid == 4) {
        // w_in_t[i][o] = g_in[o] * v_in[o][i] / ||v_in[o,:]||
        __shared__ float part[8][33];
        __shared__ float rn[8];
        int o = tid >> 5;       // 0..7
        int g = tid & 31;       // 0..31
        float s = 0.f;
        for (int i = g * 16; i < g * 16 + 16; ++i) { float x = v_in[o * 512 + i]; s += x * x; }
        part[o][g] = s;
        __syncthreads();
        if (tid < 8) {
            float t2 = 0.f;
            for (int gg = 0; gg < 32; ++gg) t2 += part[tid][gg];
            rn[tid] = g_in[tid] / sqrtf(t2);
        }
        __syncthreads();
        for (int ii = 0; ii < 2; ++ii) {
            int i = tid * 2 + ii;
#pragma unroll
            for (int oo = 0; oo < 8; ++oo)
                ws[WS_WIN_T + i * 8 + oo] = v_in[oo * 512 + i] * rn[oo];
        }
    } else {
        // w_out rows (bid 5,6): norm over 8 elems per row
        int o = (bid - 5) * 256 + tid;
        const float* vr = v_out + (size_t)o * 8;
        float v[8]; float s = 0.f;
#pragma unroll
        for (int j = 0; j < 8; ++j) { v[j] = vr[j]; s += v[j] * v[j]; }
        float rn = g_out[o] / sqrtf(s);
#pragma unroll
        for (int j = 0; j < 8; ++j) ws[WS_WOUT + o * 8 + j] = v[j] * rn;
    }
}

// ---------------- k1: in_proj partials, 4 tokens/thread ----------------------
// grid (64, 8): blockIdx.x = 1024-token block, blockIdx.y = D-chunk (64 rows).
__global__ __launch_bounds__(256) void k1_inproj(const float* __restrict__ z,
                                                 const float* __restrict__ ws_w,
                                                 float* __restrict__ ws_zep) {
    __shared__ float w[512];   // w_in_t chunk [64][8]
    int tid = threadIdx.x;
    int c = blockIdx.y;
    if (tid < 128)
        ((float4*)w)[tid] = ((const float4*)(ws_w + c * 512))[tid];
    __syncthreads();

    int tok0 = blockIdx.x * 1024 + tid * 4;
    int b = tok0 >> 12;
    int t = tok0 & (T_ - 1);

    float a[4][8];
#pragma unroll
    for (int j = 0; j < 4; ++j)
#pragma unroll
        for (int o = 0; o < 8; ++o) a[j][o] = 0.f;

    const float4* zp4 = (const float4*)(z + (size_t)b * D_ * T_ + (size_t)(c * 64) * T_ + t);
#pragma unroll 8
    for (int i = 0; i < 64; ++i) {
        float4 v = zp4[(size_t)i * (T_ / 4)];
        float4 wa = ((float4*)w)[i * 2];
        float4 wb = ((float4*)w)[i * 2 + 1];
        float vv[4] = {v.x, v.y, v.z, v.w};
#pragma unroll
        for (int j = 0; j < 4; ++j) {
            a[j][0] = fmaf(wa.x, vv[j], a[j][0]);
            a[j][1] = fmaf(wa.y, vv[j], a[j][1]);
            a[j][2] = fmaf(wa.z, vv[j], a[j][2]);
            a[j][3] = fmaf(wa.w, vv[j], a[j][3]);
            a[j][4] = fmaf(wb.x, vv[j], a[j][4]);
            a[j][5] = fmaf(wb.y, vv[j], a[j][5]);
            a[j][6] = fmaf(wb.z, vv[j], a[j][6]);
            a[j][7] = fmaf(wb.w, vv[j], a[j][7]);
        }
    }
#pragma unroll
    for (int j = 0; j < 4; ++j) {
        float4* zo = (float4*)(ws_zep + ((size_t)c * NTOK_ + tok0 + j) * 8);
        zo[0] = make_float4(a[j][0], a[j][1], a[j][2], a[j][3]);
        zo[1] = make_float4(a[j][4], a[j][5], a[j][6], a[j][7]);
    }
}

// ---------------- k2: partial-reduce + nearest-codebook search ---------------
// 1024 blocks x 128 threads (2 waves). Each wave holds the FULL codebook in
// registers (16 entries/lane) and scans 32 tokens broadcast from LDS.
__global__ __launch_bounds__(128) void k2_search(const float* __restrict__ ws,
                                                 const float* __restrict__ b_in,
                                                 float* __restrict__ out_idx_f,
                                                 int* __restrict__ ws_idx,
                                                 float* __restrict__ ws_bpart) {
    __shared__ float zes[64 * 8];
    __shared__ float2 qlds[1024];   // ||q||, ||q||^2
    __shared__ float wl[2];
    int tid = threadIdx.x;
    int lane = tid & 63;
    int wv = tid >> 6;

    int base = blockIdx.x * 64;
    // stage 64 tokens of z_e = sum of 8 chunk-partials + bias
    {
        float4 bia = ((const float4*)b_in)[tid & 1];
        const float4* zp = (const float4*)(ws + WS_ZEP);
        size_t o = (size_t)base * 2 + tid;
        float4 s = bia;
#pragma unroll
        for (int c = 0; c < 8; ++c) {
            float4 v = zp[(size_t)c * (NTOK_ * 2) + o];
            s.x += v.x; s.y += v.y; s.z += v.z; s.w += v.w;
        }
        ((float4*)zes)[tid] = s;
    }
    // stage ||q|| table
    {
        const float2* qsrc = (const float2*)(ws + WS_QN);
#pragma unroll
        for (int k = 0; k < 8; ++k) qlds[tid + k * 128] = qsrc[tid + k * 128];
    }

    // load 16 codebook entries per lane: e = k*64 + lane
    float cbn[16][8]; float cc[16];
    const float* cb = ws + WS_CBN;
#pragma unroll
    for (int k = 0; k < 16; ++k) {
        const float* p = cb + (size_t)(k * 64 + lane) * 9;
#pragma unroll
        for (int j = 0; j < 8; ++j) cbn[k][j] = p[j];
        cc[k] = p[8];
    }
    __syncthreads();

    float lossAcc = 0.f;
    for (int s = 0; s < 32; ++s) {
        int tl = wv * 32 + s;
        int tok = base + tl;
        float4 z0 = ((float4*)zes)[tl * 2];
        float4 z1 = ((float4*)zes)[tl * 2 + 1];
        float nrm2 = z0.x * z0.x + z0.y * z0.y + z0.z * z0.z + z0.w * z0.w
                   + z1.x * z1.x + z1.y * z1.y + z1.z * z1.z + z1.w * z1.w;
        float zen = fmaxf(sqrtf(nrm2), 1e-12f);
        float r = 1.0f / zen;
        float e0 = z0.x * r, e1 = z0.y * r, e2 = z0.z * r, e3 = z0.w * r;
        float e4 = z1.x * r, e5 = z1.y * r, e6 = z1.z * r, e7 = z1.w * r;
        float a = e0 * e0 + e1 * e1 + e2 * e2 + e3 * e3
                + e4 * e4 + e5 * e5 + e6 * e6 + e7 * e7;

        float best = 3.4e38f; int bidx = 0x7fffffff; float dotw = 0.f;
#pragma unroll
        for (int k = 0; k < 16; ++k) {
            float dot = cbn[k][0] * e0;
            dot = fmaf(cbn[k][1], e1, dot);
            dot = fmaf(cbn[k][2], e2, dot);
            dot = fmaf(cbn[k][3], e3, dot);
            dot = fmaf(cbn[k][4], e4, dot);
            dot = fmaf(cbn[k][5], e5, dot);
            dot = fmaf(cbn[k][6], e6, dot);
            dot = fmaf(cbn[k][7], e7, dot);
            float dist = fmaf(dot, -2.0f, a) + cc[k];   // (a - 2*dot) + c
            int e = k * 64 + lane;
            if (dist < best) { best = dist; bidx = e; dotw = dot; }
        }
        // 64-lane lexicographic (dist, idx) min reduce -> all lanes converge
#pragma unroll
        for (int off = 1; off < 64; off <<= 1) {
            float ov = __shfl_xor(best, off, 64);
            int   oi = __shfl_xor(bidx, off, 64);
            float od = __shfl_xor(dotw, off, 64);
            if (ov < best || (ov == best && oi < bidx)) { best = ov; bidx = oi; dotw = od; }
        }
        // loss = |z_e|^2 - 2*(z_e . q) + |q|^2, with z_e.q = dot * ||z_e|| * ||q||
        float2 q = qlds[bidx];
        lossAcc += nrm2 - 2.0f * dotw * zen * q.x + q.y;

        if (lane == 0) {
            out_idx_f[tok] = (float)bidx;
            ws_idx[tok] = bidx;
        }
    }
    if (lane == 0) wl[wv] = lossAcc;
    __syncthreads();
    if (tid == 0) ws_bpart[blockIdx.x] = wl[0] + wl[1];
}

// ---------------- k3: out_proj, 4 tokens/thread + loss finalize --------------
// grid (64, 8): blockIdx.x = 1024-token block, blockIdx.y = out-chunk (64 rows).
__global__ __launch_bounds__(256) void k3_outproj(const float* __restrict__ codebook,
                                                  const float* __restrict__ b_out,
                                                  const float* __restrict__ ws,
                                                  const int* __restrict__ ws_idx,
                                                  const float* __restrict__ ws_bpart,
                                                  float* __restrict__ d_out) {
    __shared__ float w[512];   // w_out chunk [64][8]
    __shared__ float bo[64];
    int tid = threadIdx.x;
    int c = blockIdx.y;
    if (tid < 128)
        ((float4*)w)[tid] = ((const float4*)(ws + WS_WOUT + c * 512))[tid];
    if (tid < 64) bo[tid] = b_out[c * 64 + tid];
    __syncthreads();

    int tok0 = blockIdx.x * 1024 + tid * 4;
    int b = tok0 >> 12;
    int t = tok0 & (T_ - 1);

    float q[4][8];
#pragma unroll
    for (int j = 0; j < 4; ++j) {
        int idx = ws_idx[tok0 + j];
        const float4* cq = (const float4*)(codebook + (size_t)idx * 8);
        float4 q0 = cq[0], q1 = cq[1];
        q[j][0] = q0.x; q[j][1] = q0.y; q[j][2] = q0.z; q[j][3] = q0.w;
        q[j][4] = q1.x; q[j][5] = q1.y; q[j][6] = q1.z; q[j][7] = q1.w;
    }

    float* op = d_out + (size_t)b * D_ * T_ + (size_t)(c * 64) * T_ + t;
#pragma unroll 8
    for (int o = 0; o < 64; ++o) {
        float4 wa = ((float4*)w)[o * 2];
        float4 wb = ((float4*)w)[o * 2 + 1];
        float bb = bo[o];
        float v[4];
#pragma unroll
        for (int j = 0; j < 4; ++j) {
            float x = bb;
            x = fmaf(wa.x, q[j][0], x); x = fmaf(wa.y, q[j][1], x);
            x = fmaf(wa.z, q[j][2], x); x = fmaf(wa.w, q[j][3], x);
            x = fmaf(wb.x, q[j][4], x); x = fmaf(wb.y, q[j][5], x);
            x = fmaf(wb.z, q[j][6], x); x = fmaf(wb.w, q[j][7], x);
            v[j] = x;
        }
        ((float4*)(op + (size_t)o * T_))[0] = make_float4(v[0], v[1], v[2], v[3]);
    }

    // finalize losses (commitment == codebook numerically)
    if (blockIdx.x == 0 && c == 0 && tid < B_) {
        float s = 0.f;
        for (int k = 0; k < 64; ++k) s += ws_bpart[tid * 64 + k];
        float m = s * (1.0f / (CD_ * T_));
        d_out[OUT_OFF_LOSS + tid] = m;
        d_out[OUT_OFF_LOSS + 16 + tid] = m;
    }
}

// ---------------- launch -----------------------------------------------------
extern "C" void kernel_launch(void* const* d_in, const int* in_sizes, int n_in,
                              void* d_out, int out_size, void* d_ws, size_t ws_size,
                              hipStream_t stream) {
    (void)in_sizes; (void)n_in; (void)out_size; (void)ws_size;
    const float* z        = (const float*)d_in[0];
    const float* v_in     = (const float*)d_in[1];
    const float* g_in     = (const float*)d_in[2];
    const float* b_in     = (const float*)d_in[3];
    const float* v_out    = (const float*)d_in[4];
    const float* g_out    = (const float*)d_in[5];
    const float* b_out    = (const float*)d_in[6];
    const float* codebook = (const float*)d_in[7];
    float* ws  = (float*)d_ws;
    float* out = (float*)d_out;

    hipLaunchKernelGGL(k0_prep, dim3(7), dim3(256), 0, stream,
                       v_in, g_in, v_out, g_out, codebook, ws);
    hipLaunchKernelGGL(k1_inproj, dim3(NTOK_ / 1024, 8), dim3(256), 0, stream,
                       z, ws + WS_WIN_T, ws + WS_ZEP);
    hipLaunchKernelGGL(k2_search, dim3(NTOK_ / 64), dim3(128), 0, stream,
                       ws, b_in, out + OUT_OFF_IDX,
                       (int*)(ws + WS_IDX), ws + WS_BPART);
    hipLaunchKernelGGL(k3_outproj, dim3(NTOK_ / 1024, 8), dim3(256), 0, stream,
                       codebook, b_out, ws, (const int*)(ws + WS_IDX),
                       ws + WS_BPART, out);
}

// Round 4
// 106.794 us; speedup vs baseline: 1.2600x; 1.2600x over previous
//
#include <hip/hip_runtime.h>
#include <math.h>

#define B_    16
#define D_    512
#define T_    4096
#define CBN_  1024
#define CD_   8
#define NTOK_ (B_ * T_)   // 65536

// ws layout (float offsets)
#define WS_WIN_T   0                        // [512][8]  w_in transposed: [i][o]
#define WS_CBN     4096                     // [1024][8] normalized codebook
#define WS_CC      12288                    // [1024]    sum(cb_n^2)
#define WS_QN      13312                    // [1024][2] ||q||, ||q||^2
#define WS_PCB     15360                    // [1024][512] w_out @ cb^T + b_out
#define WS_IDX     (15360 + 524288)         // int[65536]
#define WS_BPART   (15360 + 524288 + 65536) // float[1024] loss partials

#define OUT_OFF_LOSS 33554432               // commitment[16], then codebook[16]
#define OUT_OFF_IDX  33554464               // indices as float [65536]

// ---------------- k0: normalized codebook + w_in_t ---------------------------
__global__ __launch_bounds__(256) void k0_prep(const float* __restrict__ v_in,
                                               const float* __restrict__ g_in,
                                               const float* __restrict__ codebook,
                                               float* __restrict__ ws) {
    int bid = blockIdx.x, tid = threadIdx.x;
    if (bid < 4) {
        int e = bid * 256 + tid;
        const float* c = codebook + (size_t)e * 8;
        float v[8]; float s = 0.f;
#pragma unroll
        for (int j = 0; j < 8; ++j) { v[j] = c[j]; s += v[j] * v[j]; }
        float qn = sqrtf(s);
        float rn = 1.0f / fmaxf(qn, 1e-12f);
        float cs = 0.f;
        float* o = ws + WS_CBN + (size_t)e * 8;
#pragma unroll
        for (int j = 0; j < 8; ++j) { float cn = v[j] * rn; o[j] = cn; cs += cn * cn; }
        ws[WS_CC + e] = cs;
        ws[WS_QN + e * 2]     = qn;
        ws[WS_QN + e * 2 + 1] = s;
    } else {
        // w_in_t[i][o] = g_in[o] * v_in[o][i] / ||v_in[o,:]||
        __shared__ float part[8][33];
        __shared__ float rn[8];
        int o = tid >> 5;       // 0..7
        int g = tid & 31;       // 0..31
        float s = 0.f;
        for (int i = g * 16; i < g * 16 + 16; ++i) { float x = v_in[o * 512 + i]; s += x * x; }
        part[o][g] = s;
        __syncthreads();
        if (tid < 8) {
            float t2 = 0.f;
            for (int gg = 0; gg < 32; ++gg) t2 += part[tid][gg];
            rn[tid] = g_in[tid] / sqrtf(t2);
        }
        __syncthreads();
        for (int ii = 0; ii < 2; ++ii) {
            int i = tid * 2 + ii;
#pragma unroll
            for (int oo = 0; oo < 8; ++oo)
                ws[WS_WIN_T + i * 8 + oo] = v_in[oo * 512 + i] * rn[oo];
        }
    }
}

// ---------------- k0b: pcb[e][o] = b_out[o] + sum_j w_out[o][j]*cb[e][j] -----
__global__ __launch_bounds__(256) void k0b_pcb(const float* __restrict__ v_out,
                                               const float* __restrict__ g_out,
                                               const float* __restrict__ b_out,
                                               const float* __restrict__ codebook,
                                               float* __restrict__ ws_pcb) {
    int e = blockIdx.x, tid = threadIdx.x;
    const float4* cq = (const float4*)(codebook + (size_t)e * 8);
    float4 q0 = cq[0], q1 = cq[1];
    float2 res;
    float* rp = &res.x;
#pragma unroll
    for (int ii = 0; ii < 2; ++ii) {
        int o = tid * 2 + ii;
        const float4* vr = (const float4*)(v_out + (size_t)o * 8);
        float4 va = vr[0], vb = vr[1];
        float s = va.x * va.x + va.y * va.y + va.z * va.z + va.w * va.w
                + vb.x * vb.x + vb.y * vb.y + vb.z * vb.z + vb.w * vb.w;
        float rn = g_out[o] / sqrtf(s);
        float w0 = va.x * rn, w1 = va.y * rn, w2 = va.z * rn, w3 = va.w * rn;
        float w4 = vb.x * rn, w5 = vb.y * rn, w6 = vb.z * rn, w7 = vb.w * rn;
        float x = b_out[o];
        x = fmaf(w0, q0.x, x); x = fmaf(w1, q0.y, x);
        x = fmaf(w2, q0.z, x); x = fmaf(w3, q0.w, x);
        x = fmaf(w4, q1.x, x); x = fmaf(w5, q1.y, x);
        x = fmaf(w6, q1.z, x); x = fmaf(w7, q1.w, x);
        rp[ii] = x;
    }
    ((float2*)(ws_pcb + (size_t)e * 512))[tid] = res;
}

// ---------------- k1: fused in_proj + nearest-codebook search ----------------
// 1024 blocks x 256 threads. Block = 64 tokens. 4 waves = 4-way K-split of
// D=512 (128 rows each), lane = token. Search: wave w scans entries
// [w*256,(w+1)*256) from LDS (broadcast), cross-wave lex merge.
__global__ __launch_bounds__(256) void k1_fused(const float* __restrict__ z,
                                                const float* __restrict__ b_in,
                                                const float* __restrict__ ws,
                                                float* __restrict__ out_idx_f,
                                                int* __restrict__ ws_idx,
                                                float* __restrict__ ws_bpart) {
    __shared__ float cbn[1024 * 8];     // 32KB
    __shared__ float cc[1024];          // 4KB
    __shared__ float part[4 * 64 * 9];  // 9KB, stride 9 -> conflict-free
    __shared__ float cand_d[256];
    __shared__ int   cand_i[256];
    __shared__ float cand_w[256];

    int tid = threadIdx.x;
    int wv = tid >> 6;
    int l  = tid & 63;
    int blk = blockIdx.x;
    int b = blk >> 6;
    int tbase = (blk & 63) << 6;

    // stage codebook tables into LDS (coalesced float4)
    {
        const float4* s4 = (const float4*)(ws + WS_CBN);
#pragma unroll
        for (int k = 0; k < 8; ++k) ((float4*)cbn)[tid + k * 256] = s4[tid + k * 256];
        ((float4*)cc)[tid] = ((const float4*)(ws + WS_CC))[tid];
    }

    // in_proj partial: wave wv covers rows [wv*128, wv*128+128)
    float acc[8];
#pragma unroll
    for (int j = 0; j < 8; ++j) acc[j] = 0.f;
    {
        const float* zp = z + (size_t)b * D_ * T_ + (size_t)(wv * 128) * T_ + tbase + l;
        const float4* wp = (const float4*)(ws + WS_WIN_T + (size_t)(wv * 128) * 8);
#pragma unroll 8
        for (int i = 0; i < 128; ++i) {
            float v = zp[(size_t)i * T_];
            float4 wa = wp[i * 2];
            float4 wb = wp[i * 2 + 1];
            acc[0] = fmaf(wa.x, v, acc[0]); acc[1] = fmaf(wa.y, v, acc[1]);
            acc[2] = fmaf(wa.z, v, acc[2]); acc[3] = fmaf(wa.w, v, acc[3]);
            acc[4] = fmaf(wb.x, v, acc[4]); acc[5] = fmaf(wb.y, v, acc[5]);
            acc[6] = fmaf(wb.z, v, acc[6]); acc[7] = fmaf(wb.w, v, acc[7]);
        }
    }
    {
        float* pp = &part[(wv * 64 + l) * 9];
#pragma unroll
        for (int j = 0; j < 8; ++j) pp[j] = acc[j];
    }
    __syncthreads();

    // finalize z_e for token l (redundant in each wave; bias first, chunks ascending)
    float ze[8];
#pragma unroll
    for (int j = 0; j < 8; ++j)
        ze[j] = b_in[j] + part[(0 * 64 + l) * 9 + j] + part[(1 * 64 + l) * 9 + j]
              + part[(2 * 64 + l) * 9 + j] + part[(3 * 64 + l) * 9 + j];

    float nrm2 = ze[0] * ze[0] + ze[1] * ze[1] + ze[2] * ze[2] + ze[3] * ze[3]
               + ze[4] * ze[4] + ze[5] * ze[5] + ze[6] * ze[6] + ze[7] * ze[7];
    float zen = fmaxf(sqrtf(nrm2), 1e-12f);
    float r = 1.0f / zen;
    float e0 = ze[0] * r, e1 = ze[1] * r, e2 = ze[2] * r, e3 = ze[3] * r;
    float e4 = ze[4] * r, e5 = ze[5] * r, e6 = ze[6] * r, e7 = ze[7] * r;
    float a = e0 * e0 + e1 * e1 + e2 * e2 + e3 * e3
            + e4 * e4 + e5 * e5 + e6 * e6 + e7 * e7;

    // scan this wave's 256-entry slice (ascending, strict < -> first-min)
    float best = 3.4e38f; int bidx = 0x7fffffff; float dotw = 0.f;
    int ebase = wv * 256;
#pragma unroll 4
    for (int e = ebase; e < ebase + 256; ++e) {
        const float4* cp = (const float4*)&cbn[e * 8];
        float4 c0 = cp[0], c1 = cp[1];
        float dot = c0.x * e0;
        dot = fmaf(c0.y, e1, dot);
        dot = fmaf(c0.z, e2, dot);
        dot = fmaf(c0.w, e3, dot);
        dot = fmaf(c1.x, e4, dot);
        dot = fmaf(c1.y, e5, dot);
        dot = fmaf(c1.z, e6, dot);
        dot = fmaf(c1.w, e7, dot);
        float dist = fmaf(dot, -2.0f, a) + cc[e];   // (a - 2*dot) + c
        if (dist < best) { best = dist; bidx = e; dotw = dot; }
    }
    cand_d[wv * 64 + l] = best;
    cand_i[wv * 64 + l] = bidx;
    cand_w[wv * 64 + l] = dotw;
    __syncthreads();

    if (wv == 0) {
        float bd = cand_d[l]; int bi = cand_i[l]; float bw = cand_w[l];
#pragma unroll
        for (int w = 1; w < 4; ++w) {
            float d2 = cand_d[w * 64 + l];
            if (d2 < bd) { bd = d2; bi = cand_i[w * 64 + l]; bw = cand_w[w * 64 + l]; }
        }
        int tok = blk * 64 + l;
        ws_idx[tok] = bi;
        out_idx_f[tok] = (float)bi;
        // loss = |z_e|^2 - 2*dot*||z_e||*||q|| + |q|^2
        float2 q = *(const float2*)(ws + WS_QN + (size_t)bi * 2);
        float loss = nrm2 - 2.0f * bw * zen * q.x + q.y;
#pragma unroll
        for (int off = 1; off < 64; off <<= 1) loss += __shfl_xor(loss, off, 64);
        if (l == 0) ws_bpart[blk] = loss;
    }
}

// ---------------- k3: gather-copy out_proj + loss finalize -------------------
// grid (256, 8): blockIdx.x = token block (256 tokens), blockIdx.y = out-chunk
// (64 rows). out[b, c*64+o, t] = pcb[idx[tok]][c*64+o]  (bias baked in).
__global__ __launch_bounds__(256) void k3_gather(const float* __restrict__ ws,
                                                 const int* __restrict__ ws_idx,
                                                 const float* __restrict__ ws_bpart,
                                                 float* __restrict__ d_out) {
    int tid = threadIdx.x;
    int c = blockIdx.y;
    int tok = blockIdx.x * 256 + tid;
    int b = tok >> 12;
    int t = tok & (T_ - 1);
    int idx = ws_idx[tok];

    const float4* prow = (const float4*)(ws + WS_PCB + (size_t)idx * 512 + c * 64);
    float* op = d_out + (size_t)b * D_ * T_ + (size_t)(c * 64) * T_ + t;
#pragma unroll
    for (int k = 0; k < 16; ++k) {
        float4 v = prow[k];
        op[(size_t)(k * 4 + 0) * T_] = v.x;
        op[(size_t)(k * 4 + 1) * T_] = v.y;
        op[(size_t)(k * 4 + 2) * T_] = v.z;
        op[(size_t)(k * 4 + 3) * T_] = v.w;
    }

    if (blockIdx.x == 0 && c == 0 && tid < B_) {
        float s = 0.f;
        for (int k = 0; k < 64; ++k) s += ws_bpart[tid * 64 + k];
        float m = s * (1.0f / (CD_ * T_));
        d_out[OUT_OFF_LOSS + tid] = m;
        d_out[OUT_OFF_LOSS + 16 + tid] = m;
    }
}

// ---------------- launch -----------------------------------------------------
extern "C" void kernel_launch(void* const* d_in, const int* in_sizes, int n_in,
                              void* d_out, int out_size, void* d_ws, size_t ws_size,
                              hipStream_t stream) {
    (void)in_sizes; (void)n_in; (void)out_size; (void)ws_size;
    const float* z        = (const float*)d_in[0];
    const float* v_in     = (const float*)d_in[1];
    const float* g_in     = (const float*)d_in[2];
    const float* b_in     = (const float*)d_in[3];
    const float* v_out    = (const float*)d_in[4];
    const float* g_out    = (const float*)d_in[5];
    const float* b_out    = (const float*)d_in[6];
    const float* codebook = (const float*)d_in[7];
    float* ws  = (float*)d_ws;
    float* out = (float*)d_out;

    hipLaunchKernelGGL(k0_prep, dim3(5), dim3(256), 0, stream,
                       v_in, g_in, codebook, ws);
    hipLaunchKernelGGL(k0b_pcb, dim3(CBN_), dim3(256), 0, stream,
                       v_out, g_out, b_out, codebook, ws + WS_PCB);
    hipLaunchKernelGGL(k1_fused, dim3(NTOK_ / 64), dim3(256), 0, stream,
                       z, b_in, ws, out + OUT_OFF_IDX,
                       (int*)(ws + WS_IDX), ws + WS_BPART);
    hipLaunchKernelGGL(k3_gather, dim3(NTOK_ / 256, 8), dim3(256), 0, stream,
                       ws, (const int*)(ws + WS_IDX), ws + WS_BPART, out);
}